// Round 8
// baseline (375.890 us; speedup 1.0000x reference)
//
#include <hip/hip_runtime.h>
#include <cfloat>
#include <climits>

#define NEG 0.2f
#define GEPS 1e-5f
#define D 6
#define H 13   // 2*D+1
#define KOUT 16

#define MPAD 8192      // padded candidate capacity (NSPLIT*64 aligned)
#define NSPLIT 4       // candidate ranges (gridDim.y)
#define QW 8           // queries per wave
#define QBLK 32        // queries per block (4 waves)
#define CAP 64         // survivor slots per (query, range)
#define MARGIN 0.05f   // e-space margin covering fma-vs-reference rounding

__device__ __forceinline__ float lrelu(float x){ return x >= 0.f ? x : NEG*x; }

// atoms (n,3) -> P {x,y,z,|c|^2}, padded with never-selected sentinels
__global__ void pack_kernel(const float* __restrict__ xyz,
                            float4* __restrict__ P, int n, int npad){
  int i = blockIdx.x*blockDim.x + threadIdx.x;
  if (i >= npad) return;
  if (i < n){
    float x = xyz[3*i], y = xyz[3*i+1], z = xyz[3*i+2];
    float sq;
    {
#pragma clang fp contract(off)
      sq = (x*x + y*y) + z*z;
    }
    P[i] = make_float4(x,y,z,sq);
  } else {
    P[i] = make_float4(0.f,0.f,0.f,1e30f);  // e = 1e30 -> never survives
  }
}

// atomtypes (n,6) -> 2-layer MLP -> out (n,6)
__global__ void tt_kernel(const float* __restrict__ at_in,
                          const float* __restrict__ w1, const float* __restrict__ b1,
                          const float* __restrict__ w2, const float* __restrict__ b2,
                          float* __restrict__ out, int n){
  int i = blockIdx.x*blockDim.x + threadIdx.x;
  if (i >= n) return;
  float x[D], h[D];
  #pragma unroll
  for (int j=0;j<D;j++) x[j] = at_in[i*D+j];
  #pragma unroll
  for (int o=0;o<D;o++){
    float acc = b1[o];
    #pragma unroll
    for (int j=0;j<D;j++) acc += w1[o*D+j]*x[j];
    h[o] = lrelu(acc);
  }
  #pragma unroll
  for (int o=0;o<D;o++){
    float acc = b2[o];
    #pragma unroll
    for (int j=0;j<D;j++) acc += w2[o*D+j]*h[j];
    out[i*D+o] = acc;
  }
}

// 8 independent ascending value-sorts across 64 lanes (ILP-batched)
__device__ __forceinline__ void sort64f8(float (&v)[QW], int lane){
  #pragma unroll
  for (int k = 2; k <= 64; k <<= 1){
    #pragma unroll
    for (int j = k >> 1; j >= 1; j >>= 1){
      bool dir = ((lane & j) == 0) == ((lane & k) == 0);
      #pragma unroll
      for (int q = 0; q < QW; ++q){
        float o = __shfl_xor(v[q], j);
        v[q] = dir ? fminf(v[q], o) : fmaxf(v[q], o);
      }
    }
  }
}

// ascending lexicographic (d, i) bitonic sort across 64 lanes
__device__ __forceinline__ void sort64pair(float& d, int& i, int lane){
  #pragma unroll
  for (int k = 2; k <= 64; k <<= 1){
    #pragma unroll
    for (int j = k >> 1; j >= 1; j >>= 1){
      float od = __shfl_xor(d, j);
      int   oi = __shfl_xor(i, j);
      bool lower = (lane & j) == 0;
      bool asc   = (lane & k) == 0;
      bool oless = (od < d) || (od == d && oi < i);
      bool take  = (lower == asc) ? oless : !oless;
      d = take ? od : d;
      i = take ? oi : i;
    }
  }
}

// ascending lexicographic insert of (d,i) into sorted (td,ti)[K]
template<int K>
__device__ __forceinline__ void lex_insert(float (&td)[K], int (&ti)[K], float d, int i){
  float cd = d; int ci = i;
  #pragma unroll
  for (int t=0;t<K;++t){
    bool less = (cd < td[t]) || (cd == td[t] && ci < ti[t]);
    float nd = less ? cd : td[t]; int ni = less ? ci : ti[t];
    cd = less ? td[t] : cd;       ci = less ? ti[t] : ci;
    td[t] = nd; ti[t] = ni;
  }
}

// KNN v5: R7's register-blocked wave scan, candidate axis split NSPLIT ways
// (blockIdx.y = range). Each block: 32 queries x 2048-cand range (L1-resident).
// Pass 1: per-lane e-min per query -> T = KSEL-th smallest of 64 lane-mins
// (64 disjoint witnesses in range) + MARGIN. Pass 2: ballot-compact survivor
// indices. Phase 3: exact contract-off lex (d2,idx) sort -> sorted per-range
// top-KSEL partial (pd: f32 d2, pu: u16 idx).
template<int KSEL>
__global__ __launch_bounds__(256)
void knn5_kernel(const float4* __restrict__ candP, int niter_ps,
                 const float4* __restrict__ qarr, int nq,
                 float* __restrict__ pd, ushort* __restrict__ pu){
  __shared__ float4 qs[QBLK];
  __shared__ ushort slots[4][QW][CAP];

  const int tid  = threadIdx.x;
  const int w    = tid >> 6;
  const int lane = tid & 63;
  const int r    = blockIdx.y;
  const int rbase = r * (niter_ps*64);

  if (tid < QBLK){
    int qg = blockIdx.x*QBLK + tid;
    qs[tid] = qarr[qg < nq ? qg : nq-1];
  }
  __syncthreads();

  float q2x[QW], q2y[QW], q2z[QW];
  #pragma unroll
  for (int q = 0; q < QW; ++q){
    float4 v = qs[w*QW + q];
    q2x[q] = -2.f*v.x; q2y[q] = -2.f*v.y; q2z[q] = -2.f*v.z;
  }

  // ---------------- pass 1: per-lane e-min per query ----------------
  float mn[QW];
  #pragma unroll
  for (int q = 0; q < QW; ++q) mn[q] = FLT_MAX;

  #pragma unroll 2
  for (int it = 0; it < niter_ps; ++it){
    float4 cv = candP[rbase + it*64 + lane];
    #pragma unroll
    for (int q = 0; q < QW; ++q){
      float e = fmaf(q2x[q], cv.x, fmaf(q2y[q], cv.y, fmaf(q2z[q], cv.z, cv.w)));
      mn[q] = fminf(mn[q], e);
    }
  }

  sort64f8(mn, lane);
  float T[QW];
  #pragma unroll
  for (int q = 0; q < QW; ++q) T[q] = __shfl(mn[q], KSEL-1) + MARGIN;

  // ---------------- pass 2: ballot-compact survivors ----------------
  int cnt[QW];
  #pragma unroll
  for (int q = 0; q < QW; ++q) cnt[q] = 0;
  const unsigned long long ltmask = (1ULL << lane) - 1ULL;

  #pragma unroll 2
  for (int it = 0; it < niter_ps; ++it){
    float4 cv = candP[rbase + it*64 + lane];
    float e[QW];
    #pragma unroll
    for (int q = 0; q < QW; ++q)
      e[q] = fmaf(q2x[q], cv.x, fmaf(q2y[q], cv.y, fmaf(q2z[q], cv.z, cv.w)));
    const int j = rbase + it*64 + lane;
    #pragma unroll
    for (int q = 0; q < QW; ++q){
      bool acc = e[q] <= T[q];
      unsigned long long msk = __ballot(acc);
      if (acc){
        int ofs = cnt[q] + __popcll(msk & ltmask);
        if (ofs < CAP) slots[w][q][ofs] = (ushort)j;
      }
      cnt[q] += __popcll(msk);
    }
  }

  // ---------------- phase 3: exact per-query per-range top-KSEL ----------
  for (int q = 0; q < QW; ++q){
    const int qgq = blockIdx.x*QBLK + w*QW + q;
    if (qgq >= nq) continue;                 // wave-uniform
    const float4 qv = qs[w*QW + q];
    const int C = cnt[q];

    if (C <= CAP){
      int g = INT_MAX; float d2 = FLT_MAX;
      if (lane < C){
        g = slots[w][q][lane];
        float4 cp = candP[g];
        {
#pragma clang fp contract(off)
          float dot = qv.x*cp.x + qv.y*cp.y + qv.z*cp.z;
          d2 = (qv.w + cp.w) - 2.0f*dot;
        }
      }
      sort64pair(d2, g, lane);
      if (lane < KSEL){
        pd[(size_t)(r*KSEL + lane)*nq + qgq] = d2;
        pu[(size_t)(r*KSEL + lane)*nq + qgq] = (ushort)g;
      }
    } else if (lane == 0){
      // astronomically rare slot overflow: serial exact scan of the range
      float td[KSEL]; int ti[KSEL];
      #pragma unroll
      for (int t=0;t<KSEL;t++){ td[t]=FLT_MAX; ti[t]=INT_MAX; }
      const int rend = rbase + niter_ps*64;
      for (int jj = rbase; jj < rend; ++jj){
        float4 cp = candP[jj];
        float d2;
        {
#pragma clang fp contract(off)
          float dot = qv.x*cp.x + qv.y*cp.y + qv.z*cp.z;
          d2 = (qv.w + cp.w) - 2.0f*dot;
        }
        if ((d2 < td[KSEL-1]) || (d2 == td[KSEL-1] && jj < ti[KSEL-1]))
          lex_insert<KSEL>(td, ti, d2, jj);
      }
      for (int t=0;t<KSEL;t++){
        pd[(size_t)(r*KSEL + t)*nq + qgq] = td[t];
        pu[(size_t)(r*KSEL + t)*nq + qgq] = (ushort)ti[t];
      }
    }
  }
}

// Merge NSPLIT sorted partial lists -> final KOUT (drop OUT_OFF head = self)
template<int KSEL, int OUT_OFF>
__global__ __launch_bounds__(256)
void knn_merge_kernel(const float* __restrict__ pd, const ushort* __restrict__ pu,
                      const float4* __restrict__ candP,
                      const float4* __restrict__ qarr, int nq,
                      int* __restrict__ oidx, float* __restrict__ odist){
  const int q = blockIdx.x*256 + threadIdx.x;
  if (q >= nq) return;
  const float4 qv = qarr[q];
  float td[KSEL]; int ti[KSEL];
  #pragma unroll
  for (int t=0;t<KSEL;++t){ td[t] = FLT_MAX; ti[t] = INT_MAX; }

  for (int r = 0; r < NSPLIT; ++r){
    for (int t = 0; t < KSEL; ++t){
      float d = pd[(size_t)(r*KSEL + t)*nq + q];
      int   g = pu[(size_t)(r*KSEL + t)*nq + q];
      bool ins = (d < td[KSEL-1]) || (d == td[KSEL-1] && g < ti[KSEL-1]);
      if (!ins) break;                      // partial sorted ascending lex
      lex_insert<KSEL>(td, ti, d, g);
    }
  }

  #pragma unroll
  for (int t = OUT_OFF; t < KSEL; ++t){
    int g = ti[t];
    float4 cp = candP[g];
    float dist;
    {
#pragma clang fp contract(off)
      float dx = qv.x-cp.x, dy = qv.y-cp.y, dz = qv.z-cp.z;
      dist = (dx*dx + dy*dy) + dz*dz;
    }
    oidx[(size_t)q*KOUT + (t-OUT_OFF)]  = g;
    odist[(size_t)q*KOUT + (t-OUT_OFF)] = dist;
  }
}

// One message-passing block: out = self + lrelu(groupnorm(sum_k MLP(feat_k)))
// 4 threads per point: each handles 4 of the 16 neighbors, shfl-reduce.
template<bool SELF_ONES>
__global__ __launch_bounds__(256)
void mp_kernel(const float* __restrict__ self_feat,
               const float* __restrict__ nb_src,
               const int* __restrict__ idx,
               const float* __restrict__ dists,
               const float* __restrict__ w1g, const float* __restrict__ b1g,
               const float* __restrict__ w2g, const float* __restrict__ b2g,
               const float* __restrict__ gam, const float* __restrict__ bet,
               float* __restrict__ out, int n){
  __shared__ float w1[H*H], b1v[H], w2[D*H], b2v[D], gm[D], bt[D];
  for (int t=threadIdx.x; t<H*H; t+=blockDim.x) w1[t]=w1g[t];
  if (threadIdx.x < H) b1v[threadIdx.x]=b1g[threadIdx.x];
  for (int t=threadIdx.x; t<D*H; t+=blockDim.x) w2[t]=w2g[t];
  if (threadIdx.x < D){
    b2v[threadIdx.x]=b2g[threadIdx.x];
    gm[threadIdx.x]=gam[threadIdx.x];
    bt[threadIdx.x]=bet[threadIdx.x];
  }
  __syncthreads();
  int tt = blockIdx.x*blockDim.x + threadIdx.x;
  int p = tt >> 2, sub = tt & 3;
  if (p >= n) return;

  float s[D];
  #pragma unroll
  for (int j=0;j<D;j++) s[j] = SELF_ONES ? 1.0f : self_feat[p*D+j];
  float msg[D] = {0,0,0,0,0,0};

  #pragma unroll
  for (int u=0;u<KOUT/4;u++){
    int k = u*4 + sub;
    int j = idx[p*KOUT+k];
    float dd = dists[p*KOUT+k];
    float f[H];
    #pragma unroll
    for (int c=0;c<D;c++) f[c]=s[c];
    #pragma unroll
    for (int c=0;c<D;c++) f[D+c]=nb_src[j*D+c];
    f[2*D]=dd;
    float h[H];
    #pragma unroll
    for (int o=0;o<H;o++){
      float acc=b1v[o];
      #pragma unroll
      for (int c=0;c<H;c++) acc += w1[o*H+c]*f[c];
      h[o]=lrelu(acc);
    }
    #pragma unroll
    for (int o=0;o<D;o++){
      float acc=b2v[o];
      #pragma unroll
      for (int c=0;c<H;c++) acc += w2[o*H+c]*h[c];
      msg[o]+=acc;
    }
  }

  #pragma unroll
  for (int c=0;c<D;c++){
    msg[c] += __shfl_xor(msg[c], 1);
    msg[c] += __shfl_xor(msg[c], 2);
  }

  if (sub == 0){
    float y[D];
    #pragma unroll
    for (int gi=0; gi<2; gi++){
      float m0=msg[gi*3+0], m1=msg[gi*3+1], m2=msg[gi*3+2];
      float mu = ((m0+m1)+m2) / 3.0f;
      float d0=m0-mu, d1=m1-mu, d2v=m2-mu;
      float var = ((d0*d0 + d1*d1) + d2v*d2v) / 3.0f;
      float inv = 1.0f / sqrtf(var + GEPS);
      y[gi*3+0] = d0*inv;
      y[gi*3+1] = d1*inv;
      y[gi*3+2] = d2v*inv;
    }
    #pragma unroll
    for (int c=0;c<D;c++){
      float vv = y[c]*gm[c] + bt[c];
      out[p*D+c] = s[c] + lrelu(vv);
    }
  }
}

extern "C" void kernel_launch(void* const* d_in, const int* in_sizes, int n_in,
                              void* d_out, int out_size, void* d_ws, size_t ws_size,
                              hipStream_t stream){
  const float* xyz       = (const float*)d_in[0];
  const float* atom_xyz  = (const float*)d_in[1];
  const float* atomtypes = (const float*)d_in[2];
  const float* tt_w1 = (const float*)d_in[5];
  const float* tt_b1 = (const float*)d_in[6];
  const float* tt_w2 = (const float*)d_in[7];
  const float* tt_b2 = (const float*)d_in[8];
  const float* aa_w1 = (const float*)d_in[9];
  const float* aa_b1 = (const float*)d_in[10];
  const float* aa_w2 = (const float*)d_in[11];
  const float* aa_b2 = (const float*)d_in[12];
  const float* aa_gamma = (const float*)d_in[13];
  const float* aa_beta  = (const float*)d_in[14];
  const float* em_w1 = (const float*)d_in[15];
  const float* em_b1 = (const float*)d_in[16];
  const float* em_w2 = (const float*)d_in[17];
  const float* em_b2 = (const float*)d_in[18];
  const float* em_gamma = (const float*)d_in[19];
  const float* em_beta  = (const float*)d_in[20];

  const int n_pts = in_sizes[0]/3;
  const int n_at  = in_sizes[1]/3;
  const int niter_ps = MPAD / NSPLIT / 64;   // 32

  char* ws = (char*)d_ws;
  float4* candP = (float4*)ws; ws += (size_t)MPAD*sizeof(float4);
  float4* ptsP  = (float4*)ws; ws += (size_t)n_pts*sizeof(float4);
  float* fa   = (float*)ws; ws += (size_t)n_at*D*4;
  float* fb   = (float*)ws; ws += (size_t)n_at*D*4;
  int*   idxA = (int*)ws;   ws += (size_t)n_at*KOUT*4;
  float* distA= (float*)ws; ws += (size_t)n_at*KOUT*4;
  int*   idxP = (int*)ws;   ws += (size_t)n_pts*KOUT*4;
  float* distP= (float*)ws; ws += (size_t)n_pts*KOUT*4;
  float* ea   = (float*)ws; ws += (size_t)n_pts*D*4;
  float* eb   = (float*)ws; ws += (size_t)n_pts*D*4;
  float* pdA  = (float*)ws; ws += (size_t)NSPLIT*17*n_at*4;
  float* pdP  = (float*)ws; ws += (size_t)NSPLIT*16*n_pts*4;
  ushort* puA = (ushort*)ws; ws += (size_t)NSPLIT*17*n_at*2;
  ushort* puP = (ushort*)ws; ws += (size_t)NSPLIT*16*n_pts*2;
  float* outf = (float*)d_out;

  pack_kernel<<<(MPAD+255)/256,256,0,stream>>>(atom_xyz, candP, n_at, MPAD);
  pack_kernel<<<(n_pts+255)/256,256,0,stream>>>(xyz, ptsP, n_pts, n_pts);

  tt_kernel<<<(n_at+255)/256,256,0,stream>>>(atomtypes, tt_w1,tt_b1,tt_w2,tt_b2, fa, n_at);

  // ---- atom-atom KNN (k=17, drop self) ----
  knn5_kernel<17><<<dim3((n_at+QBLK-1)/QBLK, NSPLIT),256,0,stream>>>(
      candP, niter_ps, candP, n_at, pdA, puA);
  knn_merge_kernel<17,1><<<(n_at+255)/256,256,0,stream>>>(
      pdA, puA, candP, candP, n_at, idxA, distA);

  mp_kernel<false><<<(n_at*4+255)/256,256,0,stream>>>(fa, fa, idxA, distA,
      aa_w1+0*H*H, aa_b1+0*H, aa_w2+0*D*H, aa_b2+0*D, aa_gamma+0*D, aa_beta+0*D, fb, n_at);
  mp_kernel<false><<<(n_at*4+255)/256,256,0,stream>>>(fb, fb, idxA, distA,
      aa_w1+1*H*H, aa_b1+1*H, aa_w2+1*D*H, aa_b2+1*D, aa_gamma+1*D, aa_beta+1*D, fa, n_at);
  mp_kernel<false><<<(n_at*4+255)/256,256,0,stream>>>(fa, fa, idxA, distA,
      aa_w1+2*H*H, aa_b1+2*H, aa_w2+2*D*H, aa_b2+2*D, aa_gamma+2*D, aa_beta+2*D, fb, n_at);
  // final atom features in fb

  // ---- point-atom KNN (k=16) ----
  knn5_kernel<16><<<dim3((n_pts+QBLK-1)/QBLK, NSPLIT),256,0,stream>>>(
      candP, niter_ps, ptsP, n_pts, pdP, puP);
  knn_merge_kernel<16,0><<<(n_pts+255)/256,256,0,stream>>>(
      pdP, puP, candP, ptsP, n_pts, idxP, distP);

  mp_kernel<true ><<<(n_pts*4+255)/256,256,0,stream>>>(nullptr, fb, idxP, distP,
      em_w1+0*H*H, em_b1+0*H, em_w2+0*D*H, em_b2+0*D, em_gamma+0*D, em_beta+0*D, ea, n_pts);
  mp_kernel<false><<<(n_pts*4+255)/256,256,0,stream>>>(ea, fb, idxP, distP,
      em_w1+1*H*H, em_b1+1*H, em_w2+1*D*H, em_b2+1*D, em_gamma+1*D, em_beta+1*D, eb, n_pts);
  mp_kernel<false><<<(n_pts*4+255)/256,256,0,stream>>>(eb, fb, idxP, distP,
      em_w1+2*H*H, em_b1+2*H, em_w2+2*D*H, em_b2+2*D, em_gamma+2*D, em_beta+2*D, outf, n_pts);
}

// Round 9
// 218.886 us; speedup vs baseline: 1.7173x; 1.7173x over previous
//
#include <hip/hip_runtime.h>
#include <cfloat>
#include <climits>

#define NEG 0.2f
#define GEPS 1e-5f
#define D 6
#define H 13   // 2*D+1
#define KOUT 16

#define MPAD 8192      // padded candidate capacity (multiple of 64)
#define QW 4           // queries per wave
#define QBLK 16        // queries per block (4 waves)
#define CAP 64         // survivor slots per query
#define MARGIN 0.05f   // e-space margin covering fma-vs-reference rounding

__device__ __forceinline__ float lrelu(float x){ return x >= 0.f ? x : NEG*x; }

// atoms (n,3) -> P {x,y,z,|c|^2}, padded with never-selected sentinels
__global__ void pack_kernel(const float* __restrict__ xyz,
                            float4* __restrict__ P, int n, int npad){
  int i = blockIdx.x*blockDim.x + threadIdx.x;
  if (i >= npad) return;
  if (i < n){
    float x = xyz[3*i], y = xyz[3*i+1], z = xyz[3*i+2];
    float sq;
    {
#pragma clang fp contract(off)
      sq = (x*x + y*y) + z*z;
    }
    P[i] = make_float4(x,y,z,sq);
  } else {
    P[i] = make_float4(0.f,0.f,0.f,1e30f);  // e = 1e30 -> never survives
  }
}

// atomtypes (n,6) -> 2-layer MLP -> out (n,6)
__global__ void tt_kernel(const float* __restrict__ at_in,
                          const float* __restrict__ w1, const float* __restrict__ b1,
                          const float* __restrict__ w2, const float* __restrict__ b2,
                          float* __restrict__ out, int n){
  int i = blockIdx.x*blockDim.x + threadIdx.x;
  if (i >= n) return;
  float x[D], h[D];
  #pragma unroll
  for (int j=0;j<D;j++) x[j] = at_in[i*D+j];
  #pragma unroll
  for (int o=0;o<D;o++){
    float acc = b1[o];
    #pragma unroll
    for (int j=0;j<D;j++) acc += w1[o*D+j]*x[j];
    h[o] = lrelu(acc);
  }
  #pragma unroll
  for (int o=0;o<D;o++){
    float acc = b2[o];
    #pragma unroll
    for (int j=0;j<D;j++) acc += w2[o*D+j]*h[j];
    out[i*D+o] = acc;
  }
}

// QW independent ascending value-sorts across 64 lanes (ILP-batched)
__device__ __forceinline__ void sort64fq(float (&v)[QW], int lane){
  #pragma unroll
  for (int k = 2; k <= 64; k <<= 1){
    #pragma unroll
    for (int j = k >> 1; j >= 1; j >>= 1){
      bool dir = ((lane & j) == 0) == ((lane & k) == 0);
      #pragma unroll
      for (int q = 0; q < QW; ++q){
        float o = __shfl_xor(v[q], j);
        v[q] = dir ? fminf(v[q], o) : fmaxf(v[q], o);
      }
    }
  }
}

// ascending lexicographic (d, i) bitonic sort across 64 lanes
__device__ __forceinline__ void sort64pair(float& d, int& i, int lane){
  #pragma unroll
  for (int k = 2; k <= 64; k <<= 1){
    #pragma unroll
    for (int j = k >> 1; j >= 1; j >>= 1){
      float od = __shfl_xor(d, j);
      int   oi = __shfl_xor(i, j);
      bool lower = (lane & j) == 0;
      bool asc   = (lane & k) == 0;
      bool oless = (od < d) || (od == d && oi < i);
      bool take  = (lower == asc) ? oless : !oless;
      d = take ? od : d;
      i = take ? oi : i;
    }
  }
}

// KNN v6: R7's register-blocked wave scan with QW=4 (more waves -> occupancy).
// Pass 1: per-lane e-min per query (e = |c|^2 - 2 q.c via fma; values only).
// T(q) = KSEL-th smallest of 64 lane-mins (64 disjoint witnesses) + MARGIN.
// Pass 2: survivors -> per-(wave,query) LDS slots via rare-path atomicAdd
// (unordered; phase 3 sorts exactly). Phase 3: exact contract-off lex
// (d2, idx) sort across lanes, emit KOUT from OUT_OFF.
template<int KSEL, int OUT_OFF>
__global__ __launch_bounds__(256)
void knn6_kernel(const float4* __restrict__ candP, int ncand, int niter,
                 const float4* __restrict__ qarr, int nq,
                 int* __restrict__ oidx, float* __restrict__ odist){
  __shared__ float4 qs[QBLK];
  __shared__ ushort slots[4][QW][CAP];
  __shared__ int    scnt[4][QW];

  const int tid  = threadIdx.x;
  const int w    = tid >> 6;
  const int lane = tid & 63;

  if (tid < QBLK){
    int qg = blockIdx.x*QBLK + tid;
    qs[tid] = qarr[qg < nq ? qg : nq-1];
  }
  if (lane < QW) scnt[w][lane] = 0;          // own wave's counters
  __syncthreads();

  // -2*q in registers (e = fma(q2x,cx, fma(q2y,cy, fma(q2z,cz, cw))))
  float q2x[QW], q2y[QW], q2z[QW];
  #pragma unroll
  for (int q = 0; q < QW; ++q){
    float4 v = qs[w*QW + q];
    q2x[q] = -2.f*v.x; q2y[q] = -2.f*v.y; q2z[q] = -2.f*v.z;
  }

  // ---------------- pass 1: per-lane e-min per query ----------------
  float mn[QW];
  #pragma unroll
  for (int q = 0; q < QW; ++q) mn[q] = FLT_MAX;

  #pragma unroll 4
  for (int it = 0; it < niter; ++it){
    float4 cv = candP[it*64 + lane];
    #pragma unroll
    for (int q = 0; q < QW; ++q){
      float e = fmaf(q2x[q], cv.x, fmaf(q2y[q], cv.y, fmaf(q2z[q], cv.z, cv.w)));
      mn[q] = fminf(mn[q], e);
    }
  }

  // threshold per query: KSEL-th smallest lane-min + margin
  sort64fq(mn, lane);
  float T[QW];
  #pragma unroll
  for (int q = 0; q < QW; ++q) T[q] = __shfl(mn[q], KSEL-1) + MARGIN;

  // ---------------- pass 2: collect survivors (rare-path atomics) --------
  #pragma unroll 4
  for (int it = 0; it < niter; ++it){
    float4 cv = candP[it*64 + lane];
    const int j = it*64 + lane;
    #pragma unroll
    for (int q = 0; q < QW; ++q){
      float e = fmaf(q2x[q], cv.x, fmaf(q2y[q], cv.y, fmaf(q2z[q], cv.z, cv.w)));
      if (e <= T[q]){
        int ofs = atomicAdd(&scnt[w][q], 1);
        if (ofs < CAP) slots[w][q][ofs] = (ushort)j;
      }
    }
  }

  // ---------------- phase 3: exact per-query select ----------------
  for (int q = 0; q < QW; ++q){
    const int qgq = blockIdx.x*QBLK + w*QW + q;
    if (qgq >= nq) continue;                 // wave-uniform
    const float4 qv = qs[w*QW + q];
    const int C = scnt[w][q];

    if (C <= CAP){
      int g = INT_MAX; float d2 = FLT_MAX;
      if (lane < C){
        g = slots[w][q][lane];
        float4 cp = candP[g];
        {
#pragma clang fp contract(off)
          float dot = qv.x*cp.x + qv.y*cp.y + qv.z*cp.z;
          d2 = (qv.w + cp.w) - 2.0f*dot;
        }
      }
      sort64pair(d2, g, lane);
      if (lane >= OUT_OFF && lane < OUT_OFF + KOUT){
        float4 cp = candP[g];
        float dist;
        {
#pragma clang fp contract(off)
          float dx = qv.x-cp.x, dy = qv.y-cp.y, dz = qv.z-cp.z;
          dist = (dx*dx + dy*dy) + dz*dz;
        }
        oidx[(size_t)qgq*KOUT + (lane-OUT_OFF)]  = g;
        odist[(size_t)qgq*KOUT + (lane-OUT_OFF)] = dist;
      }
    } else if (lane == 0){
      // astronomically rare slot overflow: serial exact full scan
      float bd[KSEL]; int bi[KSEL];
      #pragma unroll
      for (int t=0;t<KSEL;t++){ bd[t]=FLT_MAX; bi[t]=INT_MAX; }
      float cmd = FLT_MAX; int cmi = INT_MAX;
      for (int jj = 0; jj < ncand; ++jj){
        float4 cp = candP[jj];
        float d2;
        {
#pragma clang fp contract(off)
          float dot = qv.x*cp.x + qv.y*cp.y + qv.z*cp.z;
          d2 = (qv.w + cp.w) - 2.0f*dot;
        }
        if (d2 < cmd || (d2 == cmd && jj < cmi)){
          int rt = 0; float rmd=-FLT_MAX; int rmi=-1;
          for (int t=0;t<KSEL;t++){
            if (bd[t] > rmd || (bd[t]==rmd && bi[t]>rmi)){ rmd=bd[t]; rmi=bi[t]; rt=t; }
          }
          bd[rt]=d2; bi[rt]=jj;
          cmd=-FLT_MAX; cmi=-1;
          for (int t=0;t<KSEL;t++){
            if (bd[t] > cmd || (bd[t]==cmd && bi[t]>cmi)){ cmd=bd[t]; cmi=bi[t]; }
          }
        }
      }
      for (int t=0;t<KSEL;t++){
        int rt=-1; float mnd=FLT_MAX; int mni=INT_MAX;
        for (int u2=0;u2<KSEL;u2++){
          if (bd[u2] < mnd || (bd[u2]==mnd && bi[u2]<mni)){ mnd=bd[u2]; mni=bi[u2]; rt=u2; }
        }
        bd[rt]=FLT_MAX; bi[rt]=INT_MAX;
        if (t >= OUT_OFF){
          float4 cp = candP[mni];
          float dist;
          {
#pragma clang fp contract(off)
            float dx=qv.x-cp.x, dy=qv.y-cp.y, dz=qv.z-cp.z;
            dist = (dx*dx + dy*dy) + dz*dz;
          }
          oidx[(size_t)qgq*KOUT + (t-OUT_OFF)]  = mni;
          odist[(size_t)qgq*KOUT + (t-OUT_OFF)] = dist;
        }
      }
    }
  }
}

// One message-passing block: out = self + lrelu(groupnorm(sum_k MLP(feat_k)))
// 4 threads per point: each handles 4 of the 16 neighbors, shfl-reduce.
template<bool SELF_ONES>
__global__ __launch_bounds__(256)
void mp_kernel(const float* __restrict__ self_feat,
               const float* __restrict__ nb_src,
               const int* __restrict__ idx,
               const float* __restrict__ dists,
               const float* __restrict__ w1g, const float* __restrict__ b1g,
               const float* __restrict__ w2g, const float* __restrict__ b2g,
               const float* __restrict__ gam, const float* __restrict__ bet,
               float* __restrict__ out, int n){
  __shared__ float w1[H*H], b1v[H], w2[D*H], b2v[D], gm[D], bt[D];
  for (int t=threadIdx.x; t<H*H; t+=blockDim.x) w1[t]=w1g[t];
  if (threadIdx.x < H) b1v[threadIdx.x]=b1g[threadIdx.x];
  for (int t=threadIdx.x; t<D*H; t+=blockDim.x) w2[t]=w2g[t];
  if (threadIdx.x < D){
    b2v[threadIdx.x]=b2g[threadIdx.x];
    gm[threadIdx.x]=gam[threadIdx.x];
    bt[threadIdx.x]=bet[threadIdx.x];
  }
  __syncthreads();
  int tt = blockIdx.x*blockDim.x + threadIdx.x;
  int p = tt >> 2, sub = tt & 3;
  if (p >= n) return;

  float s[D];
  #pragma unroll
  for (int j=0;j<D;j++) s[j] = SELF_ONES ? 1.0f : self_feat[p*D+j];
  float msg[D] = {0,0,0,0,0,0};

  #pragma unroll
  for (int u=0;u<KOUT/4;u++){
    int k = u*4 + sub;
    int j = idx[p*KOUT+k];
    float dd = dists[p*KOUT+k];
    float f[H];
    #pragma unroll
    for (int c=0;c<D;c++) f[c]=s[c];
    #pragma unroll
    for (int c=0;c<D;c++) f[D+c]=nb_src[j*D+c];
    f[2*D]=dd;
    float h[H];
    #pragma unroll
    for (int o=0;o<H;o++){
      float acc=b1v[o];
      #pragma unroll
      for (int c=0;c<H;c++) acc += w1[o*H+c]*f[c];
      h[o]=lrelu(acc);
    }
    #pragma unroll
    for (int o=0;o<D;o++){
      float acc=b2v[o];
      #pragma unroll
      for (int c=0;c<H;c++) acc += w2[o*H+c]*h[c];
      msg[o]+=acc;
    }
  }

  #pragma unroll
  for (int c=0;c<D;c++){
    msg[c] += __shfl_xor(msg[c], 1);
    msg[c] += __shfl_xor(msg[c], 2);
  }

  if (sub == 0){
    float y[D];
    #pragma unroll
    for (int gi=0; gi<2; gi++){
      float m0=msg[gi*3+0], m1=msg[gi*3+1], m2=msg[gi*3+2];
      float mu = ((m0+m1)+m2) / 3.0f;
      float d0=m0-mu, d1=m1-mu, d2v=m2-mu;
      float var = ((d0*d0 + d1*d1) + d2v*d2v) / 3.0f;
      float inv = 1.0f / sqrtf(var + GEPS);
      y[gi*3+0] = d0*inv;
      y[gi*3+1] = d1*inv;
      y[gi*3+2] = d2v*inv;
    }
    #pragma unroll
    for (int c=0;c<D;c++){
      float vv = y[c]*gm[c] + bt[c];
      out[p*D+c] = s[c] + lrelu(vv);
    }
  }
}

extern "C" void kernel_launch(void* const* d_in, const int* in_sizes, int n_in,
                              void* d_out, int out_size, void* d_ws, size_t ws_size,
                              hipStream_t stream){
  const float* xyz       = (const float*)d_in[0];
  const float* atom_xyz  = (const float*)d_in[1];
  const float* atomtypes = (const float*)d_in[2];
  const float* tt_w1 = (const float*)d_in[5];
  const float* tt_b1 = (const float*)d_in[6];
  const float* tt_w2 = (const float*)d_in[7];
  const float* tt_b2 = (const float*)d_in[8];
  const float* aa_w1 = (const float*)d_in[9];
  const float* aa_b1 = (const float*)d_in[10];
  const float* aa_w2 = (const float*)d_in[11];
  const float* aa_b2 = (const float*)d_in[12];
  const float* aa_gamma = (const float*)d_in[13];
  const float* aa_beta  = (const float*)d_in[14];
  const float* em_w1 = (const float*)d_in[15];
  const float* em_b1 = (const float*)d_in[16];
  const float* em_w2 = (const float*)d_in[17];
  const float* em_b2 = (const float*)d_in[18];
  const float* em_gamma = (const float*)d_in[19];
  const float* em_beta  = (const float*)d_in[20];

  const int n_pts = in_sizes[0]/3;
  const int n_at  = in_sizes[1]/3;
  const int npad  = (n_at + 63) & ~63;
  const int niter = npad / 64;

  char* ws = (char*)d_ws;
  float4* candP = (float4*)ws; ws += (size_t)MPAD*sizeof(float4);
  float4* ptsP  = (float4*)ws; ws += (size_t)n_pts*sizeof(float4);
  float* fa   = (float*)ws; ws += (size_t)n_at*D*4;
  float* fb   = (float*)ws; ws += (size_t)n_at*D*4;
  int*   idxA = (int*)ws;   ws += (size_t)n_at*KOUT*4;
  float* distA= (float*)ws; ws += (size_t)n_at*KOUT*4;
  int*   idxP = (int*)ws;   ws += (size_t)n_pts*KOUT*4;
  float* distP= (float*)ws; ws += (size_t)n_pts*KOUT*4;
  float* ea   = (float*)ws; ws += (size_t)n_pts*D*4;
  float* eb   = (float*)ws; ws += (size_t)n_pts*D*4;
  float* outf = (float*)d_out;

  pack_kernel<<<(npad+255)/256,256,0,stream>>>(atom_xyz, candP, n_at, npad);
  pack_kernel<<<(n_pts+255)/256,256,0,stream>>>(xyz, ptsP, n_pts, n_pts);

  tt_kernel<<<(n_at+255)/256,256,0,stream>>>(atomtypes, tt_w1,tt_b1,tt_w2,tt_b2, fa, n_at);

  // ---- atom-atom KNN (k=17, drop self) ----
  knn6_kernel<17,1><<<(n_at+QBLK-1)/QBLK,256,0,stream>>>(
      candP, n_at, niter, candP, n_at, idxA, distA);

  mp_kernel<false><<<(n_at*4+255)/256,256,0,stream>>>(fa, fa, idxA, distA,
      aa_w1+0*H*H, aa_b1+0*H, aa_w2+0*D*H, aa_b2+0*D, aa_gamma+0*D, aa_beta+0*D, fb, n_at);
  mp_kernel<false><<<(n_at*4+255)/256,256,0,stream>>>(fb, fb, idxA, distA,
      aa_w1+1*H*H, aa_b1+1*H, aa_w2+1*D*H, aa_b2+1*D, aa_gamma+1*D, aa_beta+1*D, fa, n_at);
  mp_kernel<false><<<(n_at*4+255)/256,256,0,stream>>>(fa, fa, idxA, distA,
      aa_w1+2*H*H, aa_b1+2*H, aa_w2+2*D*H, aa_b2+2*D, aa_gamma+2*D, aa_beta+2*D, fb, n_at);
  // final atom features in fb

  // ---- point-atom KNN (k=16) ----
  knn6_kernel<16,0><<<(n_pts+QBLK-1)/QBLK,256,0,stream>>>(
      candP, n_at, niter, ptsP, n_pts, idxP, distP);

  mp_kernel<true ><<<(n_pts*4+255)/256,256,0,stream>>>(nullptr, fb, idxP, distP,
      em_w1+0*H*H, em_b1+0*H, em_w2+0*D*H, em_b2+0*D, em_gamma+0*D, em_beta+0*D, ea, n_pts);
  mp_kernel<false><<<(n_pts*4+255)/256,256,0,stream>>>(ea, fb, idxP, distP,
      em_w1+1*H*H, em_b1+1*H, em_w2+1*D*H, em_b2+1*D, em_gamma+1*D, em_beta+1*D, eb, n_pts);
  mp_kernel<false><<<(n_pts*4+255)/256,256,0,stream>>>(eb, fb, idxP, distP,
      em_w1+2*H*H, em_b1+2*H, em_w2+2*D*H, em_b2+2*D, em_gamma+2*D, em_beta+2*D, outf, n_pts);
}